// Round 12
// baseline (198.429 us; speedup 1.0000x reference)
//
#include <hip/hip_runtime.h>

#define N_NODES 100000
#define N_EDGES 2000000

typedef __bf16 bf16x8 __attribute__((ext_vector_type(8)));
typedef float f32x4 __attribute__((ext_vector_type(4)));
typedef float f32x16 __attribute__((ext_vector_type(16)));

#define AS1 __attribute__((address_space(1)))
#define AS3 __attribute__((address_space(3)))

struct TrueTag { static constexpr bool value = true; };
struct FalseTag { static constexpr bool value = false; };

__device__ __forceinline__ unsigned f2bf_rne(float f) {
  unsigned u = __builtin_bit_cast(unsigned, f);
  u += 0x7FFFu + ((u >> 16) & 1u);
  return u >> 16;
}

// Pack two NON-NEGATIVE f32 into bf16x2, round-half-up.
__device__ __forceinline__ unsigned pack_rhu(float lo, float hi) {
  unsigned ulo = __builtin_bit_cast(unsigned, lo) + 0x8000u;
  unsigned uhi = __builtin_bit_cast(unsigned, hi) + 0x8000u;
  return __builtin_amdgcn_perm(uhi, ulo, 0x07060302u);
}

// |a-b| on a packed bf16 pair -> packed bf16 pair.
__device__ __forceinline__ unsigned absdiff_pack(unsigned a, unsigned b) {
  float alo = __builtin_bit_cast(float, a << 16);
  float ahi = __builtin_bit_cast(float, a & 0xFFFF0000u);
  float blo = __builtin_bit_cast(float, b << 16);
  float bhi = __builtin_bit_cast(float, b & 0xFFFF0000u);
  return pack_rhu(fabsf(alo - blo), fabsf(ahi - bhi));
}

// ---------------------------------------------------------------------------
// Node MLP via MFMA (proven math), 3125 blocks (2 tiles/block).
// ---------------------------------------------------------------------------
__global__ __launch_bounds__(64, 1) void node_mfma_kernel(
    const float* __restrict__ X, const float* __restrict__ W1,
    const float* __restrict__ b1, const float* __restrict__ W2,
    const float* __restrict__ b2, unsigned short* __restrict__ H) {
  const int lane = threadIdx.x;
  const int l15 = lane & 15;
  const int quad = lane >> 4;

  float w1v[2][4][8], b1v[2][8];
#pragma unroll
  for (int c = 0; c < 2; ++c)
#pragma unroll
    for (int j = 0; j < 8; ++j) {
      int col = c * 32 + quad * 8 + j;
      b1v[c][j] = b1[col];
#pragma unroll
      for (int d = 0; d < 4; ++d) w1v[c][d][j] = W1[d * 64 + col];
    }

  uint4 afr[2][4];
#pragma unroll
  for (int c = 0; c < 2; ++c)
#pragma unroll
    for (int mt = 0; mt < 4; ++mt) {
      unsigned w[4];
#pragma unroll
      for (int p = 0; p < 4; ++p) {
        int k = c * 32 + quad * 8 + 2 * p;
        unsigned lo = f2bf_rne(W2[k * 64 + mt * 16 + l15]);
        unsigned hi = f2bf_rne(W2[(k + 1) * 64 + mt * 16 + l15]);
        w[p] = lo | (hi << 16);
      }
      afr[c][mt] = make_uint4(w[0], w[1], w[2], w[3]);
    }
  float b2v[16];
#pragma unroll
  for (int mt = 0; mt < 4; ++mt)
#pragma unroll
    for (int r = 0; r < 4; ++r) b2v[mt * 4 + r] = b2[mt * 16 + quad * 4 + r];

  const int ntiles = N_NODES / 16;  // 6250
  for (int tile = blockIdx.x; tile < ntiles; tile += gridDim.x) {
    float4 xv = ((const float4*)X)[tile * 16 + l15];

    uint4 bfr[2];
#pragma unroll
    for (int c = 0; c < 2; ++c) {
      unsigned w[4];
#pragma unroll
      for (int p = 0; p < 4; ++p) {
        float h0 = fmaxf(b1v[c][2 * p] + xv.x * w1v[c][0][2 * p] +
                             xv.y * w1v[c][1][2 * p] + xv.z * w1v[c][2][2 * p] +
                             xv.w * w1v[c][3][2 * p],
                         0.f);
        float h1 = fmaxf(b1v[c][2 * p + 1] + xv.x * w1v[c][0][2 * p + 1] +
                             xv.y * w1v[c][1][2 * p + 1] +
                             xv.z * w1v[c][2][2 * p + 1] +
                             xv.w * w1v[c][3][2 * p + 1],
                         0.f);
        w[p] = pack_rhu(h0, h1);
      }
      bfr[c] = make_uint4(w[0], w[1], w[2], w[3]);
    }

    f32x4 acc[4];
#pragma unroll
    for (int mt = 0; mt < 4; ++mt) acc[mt] = (f32x4){0.f, 0.f, 0.f, 0.f};
#pragma unroll
    for (int c = 0; c < 2; ++c)
#pragma unroll
      for (int mt = 0; mt < 4; ++mt)
        acc[mt] = __builtin_amdgcn_mfma_f32_16x16x32_bf16(
            __builtin_bit_cast(bf16x8, afr[c][mt]),
            __builtin_bit_cast(bf16x8, bfr[c]), acc[mt], 0, 0, 0);

    unsigned short* hrow = H + (tile * 16 + l15) * 64;
#pragma unroll
    for (int mt = 0; mt < 4; ++mt) {
      unsigned lo = pack_rhu(fmaxf(acc[mt][0] + b2v[mt * 4 + 0], 0.f),
                             fmaxf(acc[mt][1] + b2v[mt * 4 + 1], 0.f));
      unsigned hi = pack_rhu(fmaxf(acc[mt][2] + b2v[mt * 4 + 2], 0.f),
                             fmaxf(acc[mt][3] + b2v[mt * 4 + 3], 0.f));
      *(uint2*)(hrow + mt * 16 + quad * 4) = make_uint2(lo, hi);
    }
  }
}

// ---------------------------------------------------------------------------
// Edge MLP v11: ONE 1024-thread block per CU = 16 waves/CU = 4 waves/SIMD.
//
// r10/r11 post-mortems: the 2x512-thread route to 16 waves/CU failed twice
// ((512,4): allocator spill; (512,3): 2x78.3KB blocks didn't co-schedule ->
// occupancy FELL to 1 block/CU). A single 1024-thread block owns the whole
// CU: no LDS packing race, no pairing uncertainty. LDS = 16x8KB gbuf + 16KB
// weights + 256B = 144.25KB <= 160KB.
//
// Hard constraint: a 16-wave block requires <= 128 total regs/wave to be
// schedulable. De-risked by moving 2 more weight chunks to LDS (4 chunks in
// regs = 32, 8 chunks in LDS): arch demand ~65-70 (r11 measured 84 with 6
// reg-chunks) + 32 AGPR acc => ~100 total, safe margin under 128. Loose
// __launch_bounds__(1024,1): no allocator pressure (the r10 lesson).
//
// Per-wave structure (staging, vmcnt(4)/vmcnt(5), absdiff, epilogue) is
// byte-identical to r8's proven 71.5us kernel.
// ---------------------------------------------------------------------------
__global__ __launch_bounds__(1024, 1) void edge_mlp_kernel(
    const unsigned short* __restrict__ H, const int* __restrict__ pairs,
    const float* __restrict__ We1, const float* __restrict__ be1,
    const float* __restrict__ We2, const float* __restrict__ be2,
    float* __restrict__ out) {
  __shared__ uint4 gbuf[16][512];     // 128 KB: one 8KB row buffer per wave
  __shared__ uint4 lds_w8[8][2][64];  // 16 KB: We1^T chunks 4..11
  __shared__ float lds_c[64];         // 256 B: We2 (epilogue broadcast)

  const int tid = threadIdx.x;
  const int lane = tid & 63;
  const int n = lane & 31;       // edge within tile (readback role)
  const int half = lane >> 5;    // k-half (readback role)
  const int wave = tid >> 6;     // 0..15
  const int rowsel = lane >> 3;  // loader role: row within 8-row group
  const int swzc = (lane & 7) ^ rowsel;  // global 16B chunk to fetch

  if (tid < 64) lds_c[tid] = We2[tid];

  // Stage We1^T chunks 4..11 to LDS: wave w fills item w (16 items).
  // lds_w8[c-4][mt][lane] elem j = bf16(We1[(c*16+half*8+j)*64 + mt*32+n]).
  {
    const int c = 4 + (wave >> 1);
    const int mt = wave & 1;
    const int col = mt * 32 + n;
    const int kb = c * 16 + half * 8;
    unsigned w[4];
#pragma unroll
    for (int p = 0; p < 4; ++p)
      w[p] = f2bf_rne(We1[(kb + 2 * p) * 64 + col]) |
             (f2bf_rne(We1[(kb + 2 * p + 1) * 64 + col]) << 16);
    lds_w8[c - 4][mt][lane] = make_uint4(w[0], w[1], w[2], w[3]);
  }

  // We1^T chunks 0..3 in registers (32 VGPRs).
  uint4 afr[4][2];
#pragma unroll
  for (int c = 0; c < 4; ++c)
#pragma unroll
    for (int mt = 0; mt < 2; ++mt) {
      const int col = mt * 32 + n;
      const int kb = c * 16 + half * 8;
      unsigned w[4];
#pragma unroll
      for (int p = 0; p < 4; ++p)
        w[p] = f2bf_rne(We1[(kb + 2 * p) * 64 + col]) |
               (f2bf_rne(We1[(kb + 2 * p + 1) * 64 + col]) << 16);
      afr[c][mt] = make_uint4(w[0], w[1], w[2], w[3]);
    }
  // Bias chunk: only elem0 nonzero -> 2 regs.
  unsigned a12[2];
#pragma unroll
  for (int mt = 0; mt < 2; ++mt)
    a12[mt] = (half == 0) ? f2bf_rne(be1[mt * 32 + n]) : 0u;
  const uint4 b13u = make_uint4((half == 0) ? 0x00003F80u : 0u, 0u, 0u, 0u);
  const float be2v = be2[0];

  uint4* const buf = &gbuf[wave][0];
  int rbo[4];
#pragma unroll
  for (int c = 0; c < 4; ++c) rbo[c] = n * 8 + ((2 * c + half) ^ (n & 7));

  const int wid = blockIdx.x * 16 + wave;
  const int nw = gridDim.x * 16;  // 4096
  const int ntiles = N_EDGES / 32;
  const int last = ntiles - 1;
  const int2* pairs2 = (const int2*)pairs;

  // Weights visible to all waves; also drains vmem -> clean vmcnt state.
  __syncthreads();

  // Issue the 8 row-group gathers for one tile into buffer `dst`.
  auto issue_gathers = [&](uint4* dst, const int2* prs) {
#pragma unroll
    for (int k = 0; k < 4; ++k) {
      const AS1 unsigned* gu =
          (const AS1 unsigned*)(H + (size_t)prs[k].x * 64) + swzc * 4;
      const AS1 unsigned* gv =
          (const AS1 unsigned*)(H + (size_t)prs[k].y * 64) + swzc * 4;
      __builtin_amdgcn_global_load_lds(gu, (AS3 unsigned*)(dst + k * 64), 16,
                                       0, 0);
      __builtin_amdgcn_global_load_lds(
          gv, (AS3 unsigned*)(dst + 256 + k * 64), 16, 0, 0);
    }
  };

  // Prologue: gathers(t0) [8], then pairs(t1) [4] => 12 outstanding at iter0
  // -> vmcnt(4) retires exactly the 8 gathers.
  int2 pr[4];
  {
#pragma unroll
    for (int k = 0; k < 4; ++k) pr[k] = pairs2[wid * 32 + k * 8 + rowsel];
    issue_gathers(buf, pr);
    __builtin_amdgcn_sched_barrier(0);
    int t1 = wid + nw <= last ? wid + nw : last;
#pragma unroll
    for (int k = 0; k < 4; ++k) pr[k] = pairs2[t1 * 32 + k * 8 + rowsel];
  }

  // One tile: wait own gathers -> read rows to regs -> refill same buffer
  // for t+nw -> reload pr for t+2nw -> absdiff -> 26 MFMAs -> epilogue.
  auto body = [&](int tc, auto FIRST) {
    __builtin_amdgcn_sched_barrier(0);
    if constexpr (decltype(FIRST)::value)
      __builtin_amdgcn_s_waitcnt(0x0F74);  // vmcnt(4): iter0, no prior store
    else
      __builtin_amdgcn_s_waitcnt(0x0F75);  // vmcnt(5): steady state
    __builtin_amdgcn_sched_barrier(0);

    const int t = tc <= last ? tc : last;
    uint4 hu[4], hv[4];
#pragma unroll
    for (int c = 0; c < 4; ++c) {
      hu[c] = buf[rbo[c]];
      hv[c] = buf[256 + rbo[c]];
    }
    // Rows now (being) read to regs; fence completion, then reuse buffer.
    asm volatile("s_waitcnt lgkmcnt(0)" ::: "memory");
    __builtin_amdgcn_sched_barrier(0);
    issue_gathers(buf, pr);  // tile tc+nw, ~full tile of compute ahead
    __builtin_amdgcn_sched_barrier(0);  // pin: gathers before pairs loads
    {
      int tn = tc + 2 * nw <= last ? tc + 2 * nw : last;
#pragma unroll
      for (int k = 0; k < 4; ++k) pr[k] = pairs2[tn * 32 + k * 8 + rowsel];
    }

    uint4 ab[4];
#pragma unroll
    for (int c = 0; c < 4; ++c) {
      ab[c].x = absdiff_pack(hu[c].x, hv[c].x);
      ab[c].y = absdiff_pack(hu[c].y, hv[c].y);
      ab[c].z = absdiff_pack(hu[c].z, hv[c].z);
      ab[c].w = absdiff_pack(hu[c].w, hv[c].w);
    }

    f32x16 acc[2];
    acc[0] = (f32x16)(0.f);
    acc[1] = (f32x16)(0.f);
    // Chunks 0..3: hu, A from regs.
#pragma unroll
    for (int c = 0; c < 4; ++c) {
      const bf16x8 b = __builtin_bit_cast(bf16x8, hu[c]);
#pragma unroll
      for (int mt = 0; mt < 2; ++mt)
        acc[mt] = __builtin_amdgcn_mfma_f32_32x32x16_bf16(
            __builtin_bit_cast(bf16x8, afr[c][mt]), b, acc[mt], 0, 0, 0);
    }
    // Chunks 4..7: hv, A just-in-time from LDS.
#pragma unroll
    for (int c = 0; c < 4; ++c) {
      const bf16x8 b = __builtin_bit_cast(bf16x8, hv[c]);
#pragma unroll
      for (int mt = 0; mt < 2; ++mt) {
        const uint4 a = lds_w8[c][mt][lane];
        acc[mt] = __builtin_amdgcn_mfma_f32_32x32x16_bf16(
            __builtin_bit_cast(bf16x8, a), b, acc[mt], 0, 0, 0);
      }
    }
    // Chunks 8..11: |hu-hv|, A just-in-time from LDS.
#pragma unroll
    for (int c = 0; c < 4; ++c) {
      const bf16x8 b = __builtin_bit_cast(bf16x8, ab[c]);
#pragma unroll
      for (int mt = 0; mt < 2; ++mt) {
        const uint4 a = lds_w8[4 + c][mt][lane];
        acc[mt] = __builtin_amdgcn_mfma_f32_32x32x16_bf16(
            __builtin_bit_cast(bf16x8, a), b, acc[mt], 0, 0, 0);
      }
    }
    // Chunk 12: bias.
#pragma unroll
    for (int mt = 0; mt < 2; ++mt)
      acc[mt] = __builtin_amdgcn_mfma_f32_32x32x16_bf16(
          __builtin_bit_cast(bf16x8, make_uint4(a12[mt], 0u, 0u, 0u)),
          __builtin_bit_cast(bf16x8, b13u), acc[mt], 0, 0, 0);

    // Epilogue: relu + We2 dot (We2 broadcast from LDS).
    // acc[mt][4g+q] -> hidden row o = mt*32 + q + 8g + 4*half.
    float s = 0.f;
#pragma unroll
    for (int mt = 0; mt < 2; ++mt)
#pragma unroll
      for (int g = 0; g < 4; ++g) {
        const float4 ew = *(const float4*)&lds_c[mt * 32 + g * 8 + 4 * half];
        s += fmaxf(acc[mt][4 * g + 0], 0.f) * ew.x;
        s += fmaxf(acc[mt][4 * g + 1], 0.f) * ew.y;
        s += fmaxf(acc[mt][4 * g + 2], 0.f) * ew.z;
        s += fmaxf(acc[mt][4 * g + 3], 0.f) * ew.w;
      }
    s += __shfl_xor(s, 32);
    if (half == 0) out[t * 32 + n] = s + be2v;
  };

  int t = wid;
  body(t, TrueTag{});
  for (t += nw; t < ntiles; t += nw) body(t, FalseTag{});
}

extern "C" void kernel_launch(void* const* d_in, const int* in_sizes, int n_in,
                              void* d_out, int out_size, void* d_ws,
                              size_t ws_size, hipStream_t stream) {
  const float* X = (const float*)d_in[0];
  const int* pairs = (const int*)d_in[1];
  const float* W1 = (const float*)d_in[2];
  const float* b1 = (const float*)d_in[3];
  const float* W2 = (const float*)d_in[4];
  const float* b2 = (const float*)d_in[5];
  const float* We1 = (const float*)d_in[6];
  const float* be1 = (const float*)d_in[7];
  const float* We2 = (const float*)d_in[8];
  const float* be2 = (const float*)d_in[9];
  float* out = (float*)d_out;
  unsigned short* H = (unsigned short*)d_ws;  // 100000*64 bf16 = 12.8 MB

  node_mfma_kernel<<<3125, 64, 0, stream>>>(X, W1, b1, W2, b2, H);
  // 144.25 KB LDS/block, ~100 total regs/wave -> 1 block/CU, 16 waves/CU,
  // 4 waves/SIMD. 256 blocks = exactly one per CU.
  edge_mlp_kernel<<<256, 1024, 0, stream>>>(H, pairs, We1, be1, We2, be2,
                                            out);
}

// Round 13
// 171.251 us; speedup vs baseline: 1.1587x; 1.1587x over previous
//
#include <hip/hip_runtime.h>

#define N_NODES 100000
#define N_EDGES 2000000

typedef __bf16 bf16x8 __attribute__((ext_vector_type(8)));
typedef float f32x4 __attribute__((ext_vector_type(4)));
typedef float f32x16 __attribute__((ext_vector_type(16)));
typedef unsigned short u16x2 __attribute__((ext_vector_type(2)));

#define AS1 __attribute__((address_space(1)))
#define AS3 __attribute__((address_space(3)))

struct TrueTag { static constexpr bool value = true; };
struct FalseTag { static constexpr bool value = false; };

__device__ __forceinline__ unsigned f2bf_rne(float f) {
  unsigned u = __builtin_bit_cast(unsigned, f);
  u += 0x7FFFu + ((u >> 16) & 1u);
  return u >> 16;
}

// Pack two NON-NEGATIVE f32 into bf16x2, round-half-up.
__device__ __forceinline__ unsigned pack_rhu(float lo, float hi) {
  unsigned ulo = __builtin_bit_cast(unsigned, lo) + 0x8000u;
  unsigned uhi = __builtin_bit_cast(unsigned, hi) + 0x8000u;
  return __builtin_amdgcn_perm(uhi, ulo, 0x07060302u);
}

// Packed u16 min: for NON-NEGATIVE bf16 (post-ReLU) the 16-bit pattern is
// monotone in the float value, so integer min == float min. v_pk_min_u16.
__device__ __forceinline__ unsigned pk_min_u16(unsigned a, unsigned b) {
  u16x2 r = __builtin_elementwise_min(__builtin_bit_cast(u16x2, a),
                                      __builtin_bit_cast(u16x2, b));
  return __builtin_bit_cast(unsigned, r);
}

// ---------------------------------------------------------------------------
// Node MLP via MFMA (proven math), 3125 blocks (2 tiles/block).
// ---------------------------------------------------------------------------
__global__ __launch_bounds__(64, 1) void node_mfma_kernel(
    const float* __restrict__ X, const float* __restrict__ W1,
    const float* __restrict__ b1, const float* __restrict__ W2,
    const float* __restrict__ b2, unsigned short* __restrict__ H) {
  const int lane = threadIdx.x;
  const int l15 = lane & 15;
  const int quad = lane >> 4;

  float w1v[2][4][8], b1v[2][8];
#pragma unroll
  for (int c = 0; c < 2; ++c)
#pragma unroll
    for (int j = 0; j < 8; ++j) {
      int col = c * 32 + quad * 8 + j;
      b1v[c][j] = b1[col];
#pragma unroll
      for (int d = 0; d < 4; ++d) w1v[c][d][j] = W1[d * 64 + col];
    }

  uint4 afr[2][4];
#pragma unroll
  for (int c = 0; c < 2; ++c)
#pragma unroll
    for (int mt = 0; mt < 4; ++mt) {
      unsigned w[4];
#pragma unroll
      for (int p = 0; p < 4; ++p) {
        int k = c * 32 + quad * 8 + 2 * p;
        unsigned lo = f2bf_rne(W2[k * 64 + mt * 16 + l15]);
        unsigned hi = f2bf_rne(W2[(k + 1) * 64 + mt * 16 + l15]);
        w[p] = lo | (hi << 16);
      }
      afr[c][mt] = make_uint4(w[0], w[1], w[2], w[3]);
    }
  float b2v[16];
#pragma unroll
  for (int mt = 0; mt < 4; ++mt)
#pragma unroll
    for (int r = 0; r < 4; ++r) b2v[mt * 4 + r] = b2[mt * 16 + quad * 4 + r];

  const int ntiles = N_NODES / 16;  // 6250
  for (int tile = blockIdx.x; tile < ntiles; tile += gridDim.x) {
    float4 xv = ((const float4*)X)[tile * 16 + l15];

    uint4 bfr[2];
#pragma unroll
    for (int c = 0; c < 2; ++c) {
      unsigned w[4];
#pragma unroll
      for (int p = 0; p < 4; ++p) {
        float h0 = fmaxf(b1v[c][2 * p] + xv.x * w1v[c][0][2 * p] +
                             xv.y * w1v[c][1][2 * p] + xv.z * w1v[c][2][2 * p] +
                             xv.w * w1v[c][3][2 * p],
                         0.f);
        float h1 = fmaxf(b1v[c][2 * p + 1] + xv.x * w1v[c][0][2 * p + 1] +
                             xv.y * w1v[c][1][2 * p + 1] +
                             xv.z * w1v[c][2][2 * p + 1] +
                             xv.w * w1v[c][3][2 * p + 1],
                         0.f);
        w[p] = pack_rhu(h0, h1);
      }
      bfr[c] = make_uint4(w[0], w[1], w[2], w[3]);
    }

    f32x4 acc[4];
#pragma unroll
    for (int mt = 0; mt < 4; ++mt) acc[mt] = (f32x4){0.f, 0.f, 0.f, 0.f};
#pragma unroll
    for (int c = 0; c < 2; ++c)
#pragma unroll
      for (int mt = 0; mt < 4; ++mt)
        acc[mt] = __builtin_amdgcn_mfma_f32_16x16x32_bf16(
            __builtin_bit_cast(bf16x8, afr[c][mt]),
            __builtin_bit_cast(bf16x8, bfr[c]), acc[mt], 0, 0, 0);

    unsigned short* hrow = H + (tile * 16 + l15) * 64;
#pragma unroll
    for (int mt = 0; mt < 4; ++mt) {
      unsigned lo = pack_rhu(fmaxf(acc[mt][0] + b2v[mt * 4 + 0], 0.f),
                             fmaxf(acc[mt][1] + b2v[mt * 4 + 1], 0.f));
      unsigned hi = pack_rhu(fmaxf(acc[mt][2] + b2v[mt * 4 + 2], 0.f),
                             fmaxf(acc[mt][3] + b2v[mt * 4 + 3], 0.f));
      *(uint2*)(hrow + mt * 16 + quad * 4) = make_uint2(lo, hi);
    }
  }
}

// ---------------------------------------------------------------------------
// Edge MLP v12: r8's proven 71.5us structure with the absdiff FOLDED INTO
// THE WEIGHTS (zero MFMA delta, zero register delta -- the clean VALU cut
// r9 wasn't):
//   |hu-hv| = hu + hv - 2*min(hu,hv)
//   E@We1   = hu@(Wu+Ww) + hv@(Wv+Ww) + min@(-2*Ww)
// A-frags hold bf16(Wu+Ww) (chunks 0..3), bf16(Wv+Ww) (chunks 4..7), and
// -2*Ww (chunks 8..11; exact scale in bf16) -- all precomputed at setup.
// Per tile the 176-op absdiff block becomes 16 v_pk_min_u16 (monotone on
// the non-negative post-ReLU bf16 patterns). pmn (16 regs) replaces ab
// (16 regs) -> VGPR count unchanged from r8's spill-free 76.
// Numerics: REMOVES the ab round-half-up rounding; adds only bf16(Wu+Ww)
// weight rounding (same order as existing weight rounding).
//
// r10/r12 lesson recorded: 16 waves/CU is structurally unreachable (any
// <=128-total-reg budget splits the unified file ~64/64 and spills the
// 48-reg gather set). 12 waves/CU (256thr, (256,3), 3 blocks/CU) is the
// occupancy ceiling; everything below is byte-identical to r8.
// ---------------------------------------------------------------------------
__global__ __launch_bounds__(256, 3) void edge_mlp_kernel(
    const unsigned short* __restrict__ H, const int* __restrict__ pairs,
    const float* __restrict__ We1, const float* __restrict__ be1,
    const float* __restrict__ We2, const float* __restrict__ be2,
    float* __restrict__ out) {
  __shared__ uint4 gbuf[4][512];      // 32 KB: one 8KB row buffer per wave
  __shared__ uint4 lds_w6[6][2][64];  // 12 KB: A-frag chunks 6..11
  __shared__ float lds_c[64];         // 256 B: We2 (epilogue broadcast)

  const int tid = threadIdx.x;
  const int lane = tid & 63;
  const int n = lane & 31;       // edge within tile (readback role)
  const int half = lane >> 5;    // k-half (readback role)
  const int wave = tid >> 6;
  const int rowsel = lane >> 3;  // loader role: row within 8-row group
  const int swzc = (lane & 7) ^ rowsel;  // global 16B chunk to fetch

  if (tid < 64) lds_c[tid] = We2[tid];

  // Combined-weight A-frag element for E-chunk c, k-row kk, column col:
  //   c 0..3  (hu feed): We1[kk] + We1[kk+128]        (Wu + Ww)
  //   c 4..7  (hv feed): We1[kk] + We1[kk+64]         (Wv + Ww)
  //   c 8..11 (min feed): -2 * We1[kk]                (kk already in Ww rows)
  auto wcomb = [&](int c, int kk, int col) -> float {
    const float w = We1[kk * 64 + col];
    if (c < 4) return w + We1[(kk + 128) * 64 + col];
    if (c < 8) return w + We1[(kk + 64) * 64 + col];
    return -2.f * w;
  };

  // Stage A-frag chunks 6..11 to LDS cooperatively (wave w fills 3 items).
#pragma unroll
  for (int i = 0; i < 3; ++i) {
    const int idx = wave * 3 + i;  // 0..11
    const int c = 6 + (idx >> 1);
    const int mt = idx & 1;
    const int col = mt * 32 + n;
    const int kb = c * 16 + half * 8;
    unsigned w[4];
#pragma unroll
    for (int p = 0; p < 4; ++p)
      w[p] = f2bf_rne(wcomb(c, kb + 2 * p, col)) |
             (f2bf_rne(wcomb(c, kb + 2 * p + 1, col)) << 16);
    lds_w6[c - 6][mt][lane] = make_uint4(w[0], w[1], w[2], w[3]);
  }

  // A-frag chunks 0..5 in registers (48 VGPRs).
  uint4 afr[6][2];
#pragma unroll
  for (int c = 0; c < 6; ++c)
#pragma unroll
    for (int mt = 0; mt < 2; ++mt) {
      const int col = mt * 32 + n;
      const int kb = c * 16 + half * 8;
      unsigned w[4];
#pragma unroll
      for (int p = 0; p < 4; ++p)
        w[p] = f2bf_rne(wcomb(c, kb + 2 * p, col)) |
               (f2bf_rne(wcomb(c, kb + 2 * p + 1, col)) << 16);
      afr[c][mt] = make_uint4(w[0], w[1], w[2], w[3]);
    }
  // Bias chunk: only elem0 nonzero -> 2 regs.
  unsigned a12[2];
#pragma unroll
  for (int mt = 0; mt < 2; ++mt)
    a12[mt] = (half == 0) ? f2bf_rne(be1[mt * 32 + n]) : 0u;
  const uint4 b13u = make_uint4((half == 0) ? 0x00003F80u : 0u, 0u, 0u, 0u);
  const float be2v = be2[0];

  uint4* const buf = &gbuf[wave][0];
  int rbo[4];
#pragma unroll
  for (int c = 0; c < 4; ++c) rbo[c] = n * 8 + ((2 * c + half) ^ (n & 7));

  const int wid = blockIdx.x * 4 + wave;
  const int nw = gridDim.x * 4;  // 3072
  const int ntiles = N_EDGES / 32;
  const int last = ntiles - 1;
  const int2* pairs2 = (const int2*)pairs;

  // Weights visible to all waves; also drains vmem -> clean vmcnt state.
  __syncthreads();

  // Issue the 8 row-group gathers for one tile into buffer `dst`.
  auto issue_gathers = [&](uint4* dst, const int2* prs) {
#pragma unroll
    for (int k = 0; k < 4; ++k) {
      const AS1 unsigned* gu =
          (const AS1 unsigned*)(H + (size_t)prs[k].x * 64) + swzc * 4;
      const AS1 unsigned* gv =
          (const AS1 unsigned*)(H + (size_t)prs[k].y * 64) + swzc * 4;
      __builtin_amdgcn_global_load_lds(gu, (AS3 unsigned*)(dst + k * 64), 16,
                                       0, 0);
      __builtin_amdgcn_global_load_lds(
          gv, (AS3 unsigned*)(dst + 256 + k * 64), 16, 0, 0);
    }
  };

  // Prologue: gathers(t0) [8], then pairs(t1) [4] => 12 outstanding at iter0
  // -> vmcnt(4) retires exactly the 8 gathers.
  int2 pr[4];
  {
#pragma unroll
    for (int k = 0; k < 4; ++k) pr[k] = pairs2[wid * 32 + k * 8 + rowsel];
    issue_gathers(buf, pr);
    __builtin_amdgcn_sched_barrier(0);
    int t1 = wid + nw <= last ? wid + nw : last;
#pragma unroll
    for (int k = 0; k < 4; ++k) pr[k] = pairs2[t1 * 32 + k * 8 + rowsel];
  }

  // One tile: wait own gathers -> read rows to regs -> refill same buffer
  // for t+nw -> reload pr for t+2nw -> pk_min -> 26 MFMAs -> epilogue.
  auto body = [&](int tc, auto FIRST) {
    __builtin_amdgcn_sched_barrier(0);
    if constexpr (decltype(FIRST)::value)
      __builtin_amdgcn_s_waitcnt(0x0F74);  // vmcnt(4): iter0, no prior store
    else
      __builtin_amdgcn_s_waitcnt(0x0F75);  // vmcnt(5): steady state
    __builtin_amdgcn_sched_barrier(0);

    const int t = tc <= last ? tc : last;
    uint4 hu[4], hv[4];
#pragma unroll
    for (int c = 0; c < 4; ++c) {
      hu[c] = buf[rbo[c]];
      hv[c] = buf[256 + rbo[c]];
    }
    // Rows now (being) read to regs; fence completion, then reuse buffer.
    asm volatile("s_waitcnt lgkmcnt(0)" ::: "memory");
    __builtin_amdgcn_sched_barrier(0);
    issue_gathers(buf, pr);  // tile tc+nw, ~full tile of compute ahead
    __builtin_amdgcn_sched_barrier(0);  // pin: gathers before pairs loads
    {
      int tn = tc + 2 * nw <= last ? tc + 2 * nw : last;
#pragma unroll
      for (int k = 0; k < 4; ++k) pr[k] = pairs2[tn * 32 + k * 8 + rowsel];
    }

    // min(hu,hv), elementwise packed: 16 VALU ops total.
    uint4 pmn[4];
#pragma unroll
    for (int c = 0; c < 4; ++c) {
      pmn[c].x = pk_min_u16(hu[c].x, hv[c].x);
      pmn[c].y = pk_min_u16(hu[c].y, hv[c].y);
      pmn[c].z = pk_min_u16(hu[c].z, hv[c].z);
      pmn[c].w = pk_min_u16(hu[c].w, hv[c].w);
    }

    f32x16 acc[2];
    acc[0] = (f32x16)(0.f);
    acc[1] = (f32x16)(0.f);
    // Chunks 0..3: hu @ (Wu+Ww), A from regs.
#pragma unroll
    for (int c = 0; c < 4; ++c) {
      const bf16x8 b = __builtin_bit_cast(bf16x8, hu[c]);
#pragma unroll
      for (int mt = 0; mt < 2; ++mt)
        acc[mt] = __builtin_amdgcn_mfma_f32_32x32x16_bf16(
            __builtin_bit_cast(bf16x8, afr[c][mt]), b, acc[mt], 0, 0, 0);
    }
    // Chunks 4..5: hv[0..1] @ (Wv+Ww), A from regs.
#pragma unroll
    for (int c = 0; c < 2; ++c) {
      const bf16x8 b = __builtin_bit_cast(bf16x8, hv[c]);
#pragma unroll
      for (int mt = 0; mt < 2; ++mt)
        acc[mt] = __builtin_amdgcn_mfma_f32_32x32x16_bf16(
            __builtin_bit_cast(bf16x8, afr[4 + c][mt]), b, acc[mt], 0, 0, 0);
    }
    // Chunks 6..7: hv[2..3] @ (Wv+Ww), A just-in-time from LDS.
#pragma unroll
    for (int c = 0; c < 2; ++c) {
      const bf16x8 b = __builtin_bit_cast(bf16x8, hv[2 + c]);
#pragma unroll
      for (int mt = 0; mt < 2; ++mt) {
        const uint4 a = lds_w6[c][mt][lane];
        acc[mt] = __builtin_amdgcn_mfma_f32_32x32x16_bf16(
            __builtin_bit_cast(bf16x8, a), b, acc[mt], 0, 0, 0);
      }
    }
    // Chunks 8..11: min @ (-2*Ww), A just-in-time from LDS.
#pragma unroll
    for (int c = 0; c < 4; ++c) {
      const bf16x8 b = __builtin_bit_cast(bf16x8, pmn[c]);
#pragma unroll
      for (int mt = 0; mt < 2; ++mt) {
        const uint4 a = lds_w6[2 + c][mt][lane];
        acc[mt] = __builtin_amdgcn_mfma_f32_32x32x16_bf16(
            __builtin_bit_cast(bf16x8, a), b, acc[mt], 0, 0, 0);
      }
    }
    // Chunk 12: bias.
#pragma unroll
    for (int mt = 0; mt < 2; ++mt)
      acc[mt] = __builtin_amdgcn_mfma_f32_32x32x16_bf16(
          __builtin_bit_cast(bf16x8, make_uint4(a12[mt], 0u, 0u, 0u)),
          __builtin_bit_cast(bf16x8, b13u), acc[mt], 0, 0, 0);

    // Epilogue: relu + We2 dot (We2 broadcast from LDS).
    // acc[mt][4g+q] -> hidden row o = mt*32 + q + 8g + 4*half.
    float s = 0.f;
#pragma unroll
    for (int mt = 0; mt < 2; ++mt)
#pragma unroll
      for (int g = 0; g < 4; ++g) {
        const float4 ew = *(const float4*)&lds_c[mt * 32 + g * 8 + 4 * half];
        s += fmaxf(acc[mt][4 * g + 0], 0.f) * ew.x;
        s += fmaxf(acc[mt][4 * g + 1], 0.f) * ew.y;
        s += fmaxf(acc[mt][4 * g + 2], 0.f) * ew.z;
        s += fmaxf(acc[mt][4 * g + 3], 0.f) * ew.w;
      }
    s += __shfl_xor(s, 32);
    if (half == 0) out[t * 32 + n] = s + be2v;
  };

  int t = wid;
  body(t, TrueTag{});
  for (t += nw; t < ntiles; t += nw) body(t, FalseTag{});
}

extern "C" void kernel_launch(void* const* d_in, const int* in_sizes, int n_in,
                              void* d_out, int out_size, void* d_ws,
                              size_t ws_size, hipStream_t stream) {
  const float* X = (const float*)d_in[0];
  const int* pairs = (const int*)d_in[1];
  const float* W1 = (const float*)d_in[2];
  const float* b1 = (const float*)d_in[3];
  const float* W2 = (const float*)d_in[4];
  const float* b2 = (const float*)d_in[5];
  const float* We1 = (const float*)d_in[6];
  const float* be1 = (const float*)d_in[7];
  const float* We2 = (const float*)d_in[8];
  const float* be2 = (const float*)d_in[9];
  float* out = (float*)d_out;
  unsigned short* H = (unsigned short*)d_ws;  // 100000*64 bf16 = 12.8 MB

  node_mfma_kernel<<<3125, 64, 0, stream>>>(X, W1, b1, W2, b2, H);
  // 44.3 KB LDS/block, ~76 arch + 32 acc regs -> 3 blocks/CU, 12 waves/CU.
  // 768 blocks = exactly resident.
  edge_mlp_kernel<<<768, 256, 0, stream>>>(H, pairs, We1, be1, We2, be2, out);
}

// Round 14
// 160.486 us; speedup vs baseline: 1.2364x; 1.0671x over previous
//
#include <hip/hip_runtime.h>

#define N_NODES 100000
#define N_EDGES 2000000

typedef __bf16 bf16x8 __attribute__((ext_vector_type(8)));
typedef float f32x4 __attribute__((ext_vector_type(4)));
typedef float f32x16 __attribute__((ext_vector_type(16)));
typedef unsigned short u16x2 __attribute__((ext_vector_type(2)));

#define AS1 __attribute__((address_space(1)))
#define AS3 __attribute__((address_space(3)))

struct TrueTag { static constexpr bool value = true; };
struct FalseTag { static constexpr bool value = false; };

__device__ __forceinline__ unsigned f2bf_rne(float f) {
  unsigned u = __builtin_bit_cast(unsigned, f);
  u += 0x7FFFu + ((u >> 16) & 1u);
  return u >> 16;
}

// Pack two NON-NEGATIVE f32 into bf16x2, round-half-up.
__device__ __forceinline__ unsigned pack_rhu(float lo, float hi) {
  unsigned ulo = __builtin_bit_cast(unsigned, lo) + 0x8000u;
  unsigned uhi = __builtin_bit_cast(unsigned, hi) + 0x8000u;
  return __builtin_amdgcn_perm(uhi, ulo, 0x07060302u);
}

// Packed u16 min: for NON-NEGATIVE bf16 (post-ReLU) the 16-bit pattern is
// monotone in the float value, so integer min == float min. v_pk_min_u16.
__device__ __forceinline__ unsigned pk_min_u16(unsigned a, unsigned b) {
  u16x2 r = __builtin_elementwise_min(__builtin_bit_cast(u16x2, a),
                                      __builtin_bit_cast(u16x2, b));
  return __builtin_bit_cast(unsigned, r);
}

// ---------------------------------------------------------------------------
// Node MLP via MFMA (proven math), 3125 blocks (2 tiles/block).
// ---------------------------------------------------------------------------
__global__ __launch_bounds__(64, 1) void node_mfma_kernel(
    const float* __restrict__ X, const float* __restrict__ W1,
    const float* __restrict__ b1, const float* __restrict__ W2,
    const float* __restrict__ b2, unsigned short* __restrict__ H) {
  const int lane = threadIdx.x;
  const int l15 = lane & 15;
  const int quad = lane >> 4;

  float w1v[2][4][8], b1v[2][8];
#pragma unroll
  for (int c = 0; c < 2; ++c)
#pragma unroll
    for (int j = 0; j < 8; ++j) {
      int col = c * 32 + quad * 8 + j;
      b1v[c][j] = b1[col];
#pragma unroll
      for (int d = 0; d < 4; ++d) w1v[c][d][j] = W1[d * 64 + col];
    }

  uint4 afr[2][4];
#pragma unroll
  for (int c = 0; c < 2; ++c)
#pragma unroll
    for (int mt = 0; mt < 4; ++mt) {
      unsigned w[4];
#pragma unroll
      for (int p = 0; p < 4; ++p) {
        int k = c * 32 + quad * 8 + 2 * p;
        unsigned lo = f2bf_rne(W2[k * 64 + mt * 16 + l15]);
        unsigned hi = f2bf_rne(W2[(k + 1) * 64 + mt * 16 + l15]);
        w[p] = lo | (hi << 16);
      }
      afr[c][mt] = make_uint4(w[0], w[1], w[2], w[3]);
    }
  float b2v[16];
#pragma unroll
  for (int mt = 0; mt < 4; ++mt)
#pragma unroll
    for (int r = 0; r < 4; ++r) b2v[mt * 4 + r] = b2[mt * 16 + quad * 4 + r];

  const int ntiles = N_NODES / 16;  // 6250
  for (int tile = blockIdx.x; tile < ntiles; tile += gridDim.x) {
    float4 xv = ((const float4*)X)[tile * 16 + l15];

    uint4 bfr[2];
#pragma unroll
    for (int c = 0; c < 2; ++c) {
      unsigned w[4];
#pragma unroll
      for (int p = 0; p < 4; ++p) {
        float h0 = fmaxf(b1v[c][2 * p] + xv.x * w1v[c][0][2 * p] +
                             xv.y * w1v[c][1][2 * p] + xv.z * w1v[c][2][2 * p] +
                             xv.w * w1v[c][3][2 * p],
                         0.f);
        float h1 = fmaxf(b1v[c][2 * p + 1] + xv.x * w1v[c][0][2 * p + 1] +
                             xv.y * w1v[c][1][2 * p + 1] +
                             xv.z * w1v[c][2][2 * p + 1] +
                             xv.w * w1v[c][3][2 * p + 1],
                         0.f);
        w[p] = pack_rhu(h0, h1);
      }
      bfr[c] = make_uint4(w[0], w[1], w[2], w[3]);
    }

    f32x4 acc[4];
#pragma unroll
    for (int mt = 0; mt < 4; ++mt) acc[mt] = (f32x4){0.f, 0.f, 0.f, 0.f};
#pragma unroll
    for (int c = 0; c < 2; ++c)
#pragma unroll
      for (int mt = 0; mt < 4; ++mt)
        acc[mt] = __builtin_amdgcn_mfma_f32_16x16x32_bf16(
            __builtin_bit_cast(bf16x8, afr[c][mt]),
            __builtin_bit_cast(bf16x8, bfr[c]), acc[mt], 0, 0, 0);

    unsigned short* hrow = H + (tile * 16 + l15) * 64;
#pragma unroll
    for (int mt = 0; mt < 4; ++mt) {
      unsigned lo = pack_rhu(fmaxf(acc[mt][0] + b2v[mt * 4 + 0], 0.f),
                             fmaxf(acc[mt][1] + b2v[mt * 4 + 1], 0.f));
      unsigned hi = pack_rhu(fmaxf(acc[mt][2] + b2v[mt * 4 + 2], 0.f),
                             fmaxf(acc[mt][3] + b2v[mt * 4 + 3], 0.f));
      *(uint2*)(hrow + mt * 16 + quad * 4) = make_uint2(lo, hi);
    }
  }
}

// ---------------------------------------------------------------------------
// Edge MLP v13: r13's weight-folded math (|hu-hv| = hu+hv-2*min; 160 VALU
// ops/tile removed, MFMA count unchanged at 26) with the REGISTER PRESSURE
// RELIEVED to kill r13's spill: A-frag chunks 0..3 in regs (32 VGPR), chunks
// 4..11 in 16KB LDS (r12's proven lean split). r13 measured VGPR 84 + 27MB
// scratch writes; freeing 16 resident regs restores r8's spill-free regime
// with slack. LDS: 32KB gbuf + 16KB weights + 256B = 48.3KB -> 3 blocks/CU
// (144.9 <= 160KB), 12 waves/CU.
//   E@We1 = hu@(Wu+Ww) + hv@(Wv+Ww) + min@(-2*Ww)
// Staging/vmcnt/epilogue byte-identical to r8's proven 71.5us kernel.
// ---------------------------------------------------------------------------
__global__ __launch_bounds__(256, 3) void edge_mlp_kernel(
    const unsigned short* __restrict__ H, const int* __restrict__ pairs,
    const float* __restrict__ We1, const float* __restrict__ be1,
    const float* __restrict__ We2, const float* __restrict__ be2,
    float* __restrict__ out) {
  __shared__ uint4 gbuf[4][512];      // 32 KB: one 8KB row buffer per wave
  __shared__ uint4 lds_w8[8][2][64];  // 16 KB: A-frag chunks 4..11
  __shared__ float lds_c[64];         // 256 B: We2 (epilogue broadcast)

  const int tid = threadIdx.x;
  const int lane = tid & 63;
  const int n = lane & 31;       // edge within tile (readback role)
  const int half = lane >> 5;    // k-half (readback role)
  const int wave = tid >> 6;
  const int rowsel = lane >> 3;  // loader role: row within 8-row group
  const int swzc = (lane & 7) ^ rowsel;  // global 16B chunk to fetch

  if (tid < 64) lds_c[tid] = We2[tid];

  // Combined-weight A-frag element for E-chunk c, k-row kk, column col:
  //   c 0..3  (hu feed):  We1[kk] + We1[kk+128]       (Wu + Ww)
  //   c 4..7  (hv feed):  We1[kk] + We1[kk+64]        (Wv + Ww)
  //   c 8..11 (min feed): -2 * We1[kk]                (kk already in Ww rows)
  auto wcomb = [&](int c, int kk, int col) -> float {
    const float w = We1[kk * 64 + col];
    if (c < 4) return w + We1[(kk + 128) * 64 + col];
    if (c < 8) return w + We1[(kk + 64) * 64 + col];
    return -2.f * w;
  };

  // Stage A-frag chunks 4..11 to LDS cooperatively (wave w fills 4 items).
#pragma unroll
  for (int i = 0; i < 4; ++i) {
    const int idx = wave * 4 + i;  // 0..15
    const int c = 4 + (idx >> 1);
    const int mt = idx & 1;
    const int col = mt * 32 + n;
    const int kb = c * 16 + half * 8;
    unsigned w[4];
#pragma unroll
    for (int p = 0; p < 4; ++p)
      w[p] = f2bf_rne(wcomb(c, kb + 2 * p, col)) |
             (f2bf_rne(wcomb(c, kb + 2 * p + 1, col)) << 16);
    lds_w8[c - 4][mt][lane] = make_uint4(w[0], w[1], w[2], w[3]);
  }

  // A-frag chunks 0..3 in registers (32 VGPRs).
  uint4 afr[4][2];
#pragma unroll
  for (int c = 0; c < 4; ++c)
#pragma unroll
    for (int mt = 0; mt < 2; ++mt) {
      const int col = mt * 32 + n;
      const int kb = c * 16 + half * 8;
      unsigned w[4];
#pragma unroll
      for (int p = 0; p < 4; ++p)
        w[p] = f2bf_rne(wcomb(c, kb + 2 * p, col)) |
               (f2bf_rne(wcomb(c, kb + 2 * p + 1, col)) << 16);
      afr[c][mt] = make_uint4(w[0], w[1], w[2], w[3]);
    }
  // Bias chunk: only elem0 nonzero -> 2 regs.
  unsigned a12[2];
#pragma unroll
  for (int mt = 0; mt < 2; ++mt)
    a12[mt] = (half == 0) ? f2bf_rne(be1[mt * 32 + n]) : 0u;
  const uint4 b13u = make_uint4((half == 0) ? 0x00003F80u : 0u, 0u, 0u, 0u);
  const float be2v = be2[0];

  uint4* const buf = &gbuf[wave][0];
  int rbo[4];
#pragma unroll
  for (int c = 0; c < 4; ++c) rbo[c] = n * 8 + ((2 * c + half) ^ (n & 7));

  const int wid = blockIdx.x * 4 + wave;
  const int nw = gridDim.x * 4;  // 3072
  const int ntiles = N_EDGES / 32;
  const int last = ntiles - 1;
  const int2* pairs2 = (const int2*)pairs;

  // Weights visible to all waves; also drains vmem -> clean vmcnt state.
  __syncthreads();

  // Issue the 8 row-group gathers for one tile into buffer `dst`.
  auto issue_gathers = [&](uint4* dst, const int2* prs) {
#pragma unroll
    for (int k = 0; k < 4; ++k) {
      const AS1 unsigned* gu =
          (const AS1 unsigned*)(H + (size_t)prs[k].x * 64) + swzc * 4;
      const AS1 unsigned* gv =
          (const AS1 unsigned*)(H + (size_t)prs[k].y * 64) + swzc * 4;
      __builtin_amdgcn_global_load_lds(gu, (AS3 unsigned*)(dst + k * 64), 16,
                                       0, 0);
      __builtin_amdgcn_global_load_lds(
          gv, (AS3 unsigned*)(dst + 256 + k * 64), 16, 0, 0);
    }
  };

  // Prologue: gathers(t0) [8], then pairs(t1) [4] => 12 outstanding at iter0
  // -> vmcnt(4) retires exactly the 8 gathers.
  int2 pr[4];
  {
#pragma unroll
    for (int k = 0; k < 4; ++k) pr[k] = pairs2[wid * 32 + k * 8 + rowsel];
    issue_gathers(buf, pr);
    __builtin_amdgcn_sched_barrier(0);
    int t1 = wid + nw <= last ? wid + nw : last;
#pragma unroll
    for (int k = 0; k < 4; ++k) pr[k] = pairs2[t1 * 32 + k * 8 + rowsel];
  }

  // One tile: wait own gathers -> read rows to regs -> refill same buffer
  // for t+nw -> reload pr for t+2nw -> pk_min -> 26 MFMAs -> epilogue.
  auto body = [&](int tc, auto FIRST) {
    __builtin_amdgcn_sched_barrier(0);
    if constexpr (decltype(FIRST)::value)
      __builtin_amdgcn_s_waitcnt(0x0F74);  // vmcnt(4): iter0, no prior store
    else
      __builtin_amdgcn_s_waitcnt(0x0F75);  // vmcnt(5): steady state
    __builtin_amdgcn_sched_barrier(0);

    const int t = tc <= last ? tc : last;
    uint4 hu[4], hv[4];
#pragma unroll
    for (int c = 0; c < 4; ++c) {
      hu[c] = buf[rbo[c]];
      hv[c] = buf[256 + rbo[c]];
    }
    // Rows now (being) read to regs; fence completion, then reuse buffer.
    asm volatile("s_waitcnt lgkmcnt(0)" ::: "memory");
    __builtin_amdgcn_sched_barrier(0);
    issue_gathers(buf, pr);  // tile tc+nw, ~full tile of compute ahead
    __builtin_amdgcn_sched_barrier(0);  // pin: gathers before pairs loads
    {
      int tn = tc + 2 * nw <= last ? tc + 2 * nw : last;
#pragma unroll
      for (int k = 0; k < 4; ++k) pr[k] = pairs2[tn * 32 + k * 8 + rowsel];
    }

    // min(hu,hv), elementwise packed: 16 VALU ops total.
    uint4 pmn[4];
#pragma unroll
    for (int c = 0; c < 4; ++c) {
      pmn[c].x = pk_min_u16(hu[c].x, hv[c].x);
      pmn[c].y = pk_min_u16(hu[c].y, hv[c].y);
      pmn[c].z = pk_min_u16(hu[c].z, hv[c].z);
      pmn[c].w = pk_min_u16(hu[c].w, hv[c].w);
    }

    f32x16 acc[2];
    acc[0] = (f32x16)(0.f);
    acc[1] = (f32x16)(0.f);
    // Chunks 0..3: hu @ (Wu+Ww), A from regs.
#pragma unroll
    for (int c = 0; c < 4; ++c) {
      const bf16x8 b = __builtin_bit_cast(bf16x8, hu[c]);
#pragma unroll
      for (int mt = 0; mt < 2; ++mt)
        acc[mt] = __builtin_amdgcn_mfma_f32_32x32x16_bf16(
            __builtin_bit_cast(bf16x8, afr[c][mt]), b, acc[mt], 0, 0, 0);
    }
    // Chunks 4..7: hv @ (Wv+Ww), A just-in-time from LDS.
#pragma unroll
    for (int c = 0; c < 4; ++c) {
      const bf16x8 b = __builtin_bit_cast(bf16x8, hv[c]);
#pragma unroll
      for (int mt = 0; mt < 2; ++mt) {
        const uint4 a = lds_w8[c][mt][lane];
        acc[mt] = __builtin_amdgcn_mfma_f32_32x32x16_bf16(
            __builtin_bit_cast(bf16x8, a), b, acc[mt], 0, 0, 0);
      }
    }
    // Chunks 8..11: min @ (-2*Ww), A just-in-time from LDS.
#pragma unroll
    for (int c = 0; c < 4; ++c) {
      const bf16x8 b = __builtin_bit_cast(bf16x8, pmn[c]);
#pragma unroll
      for (int mt = 0; mt < 2; ++mt) {
        const uint4 a = lds_w8[4 + c][mt][lane];
        acc[mt] = __builtin_amdgcn_mfma_f32_32x32x16_bf16(
            __builtin_bit_cast(bf16x8, a), b, acc[mt], 0, 0, 0);
      }
    }
    // Chunk 12: bias.
#pragma unroll
    for (int mt = 0; mt < 2; ++mt)
      acc[mt] = __builtin_amdgcn_mfma_f32_32x32x16_bf16(
          __builtin_bit_cast(bf16x8, make_uint4(a12[mt], 0u, 0u, 0u)),
          __builtin_bit_cast(bf16x8, b13u), acc[mt], 0, 0, 0);

    // Epilogue: relu + We2 dot (We2 broadcast from LDS).
    // acc[mt][4g+q] -> hidden row o = mt*32 + q + 8g + 4*half.
    float s = 0.f;
#pragma unroll
    for (int mt = 0; mt < 2; ++mt)
#pragma unroll
      for (int g = 0; g < 4; ++g) {
        const float4 ew = *(const float4*)&lds_c[mt * 32 + g * 8 + 4 * half];
        s += fmaxf(acc[mt][4 * g + 0], 0.f) * ew.x;
        s += fmaxf(acc[mt][4 * g + 1], 0.f) * ew.y;
        s += fmaxf(acc[mt][4 * g + 2], 0.f) * ew.z;
        s += fmaxf(acc[mt][4 * g + 3], 0.f) * ew.w;
      }
    s += __shfl_xor(s, 32);
    if (half == 0) out[t * 32 + n] = s + be2v;
  };

  int t = wid;
  body(t, TrueTag{});
  for (t += nw; t < ntiles; t += nw) body(t, FalseTag{});
}

extern "C" void kernel_launch(void* const* d_in, const int* in_sizes, int n_in,
                              void* d_out, int out_size, void* d_ws,
                              size_t ws_size, hipStream_t stream) {
  const float* X = (const float*)d_in[0];
  const int* pairs = (const int*)d_in[1];
  const float* W1 = (const float*)d_in[2];
  const float* b1 = (const float*)d_in[3];
  const float* W2 = (const float*)d_in[4];
  const float* b2 = (const float*)d_in[5];
  const float* We1 = (const float*)d_in[6];
  const float* be1 = (const float*)d_in[7];
  const float* We2 = (const float*)d_in[8];
  const float* be2 = (const float*)d_in[9];
  float* out = (float*)d_out;
  unsigned short* H = (unsigned short*)d_ws;  // 100000*64 bf16 = 12.8 MB

  node_mfma_kernel<<<3125, 64, 0, stream>>>(X, W1, b1, W2, b2, H);
  // 48.3 KB LDS/block, ~68 arch + 32 acc regs -> 3 blocks/CU, 12 waves/CU.
  // 768 blocks = exactly resident.
  edge_mlp_kernel<<<768, 256, 0, stream>>>(H, pairs, We1, be1, We2, be2, out);
}